// Round 13
// baseline (113.855 us; speedup 1.0000x reference)
//
#include <hip/hip_runtime.h>
#include <hip/hip_fp16.h>
#include <math.h>

#define FIN_ 128

typedef _Float16 half2v __attribute__((ext_vector_type(2)));
typedef _Float16 half8v __attribute__((ext_vector_type(8)));
typedef __attribute__((ext_vector_type(4))) float float4v;

__device__ __forceinline__ half2v u2h(unsigned u) {
    union { unsigned u; half2v h; } c; c.u = u; return c.h;
}

__device__ __forceinline__ half8v cvt8(float4 a, float4 b) {
    half8v r;
    r[0] = (_Float16)a.x; r[1] = (_Float16)a.y;
    r[2] = (_Float16)a.z; r[3] = (_Float16)a.w;
    r[4] = (_Float16)b.x; r[5] = (_Float16)b.y;
    r[6] = (_Float16)b.z; r[7] = (_Float16)b.w;
    return r;
}

// ---------------- single prep kernel: rowptr (leading blocks) + all-fsel GEMM --------
// Blocks [0, nrb): rowptr[i] = lower_bound(src, i) — runs alongside gemm blocks.
// Blocks [nrb, nrb+ngb): 32-node x 384-feat GEMM tile. x read ONCE in fp32 (no xh
// round-trip, no cvt kernel); W L2-resident; in-register fp32->f16 convert.
// Wave w, frag g: feat 16-block b = w + 4g (b 0..23). acc[g][ni] maps
// feat = b*16 + kg*4 + reg, node = row0 + ni*16 + l15 (verified r5..r12 mapping).
// 3-phase transpose epilogue via T[32][136]: ph0 -> qb (x0.25), ph1 -> kv k-half,
// ph2 -> kv v-half; 16B coalesced stores.
__global__ __launch_bounds__(256) void prep_kernel(const float* __restrict__ x,
                                                   const float* __restrict__ W,
                                                   _Float16* __restrict__ qb,
                                                   _Float16* __restrict__ kv,
                                                   const int* __restrict__ src,
                                                   int* __restrict__ rowptr,
                                                   int n, int nE, int nrb) {
    const int bid = blockIdx.x;
    const int t = threadIdx.x;

    if (bid < nrb) {                          // ---- rowptr blocks (first, hidden) ----
        const int i = bid * 256 + t;
        if (i > n) return;
        int lo = 0, hi = nE;
        while (lo < hi) {
            int mid = (lo + hi) >> 1;
            if (src[mid] < i) lo = mid + 1; else hi = mid;
        }
        rowptr[i] = lo;
        return;
    }

    // ---- GEMM block: 32 nodes x 384 feats ----
    __shared__ _Float16 T[32][136];           // 8.7 KB
    const int row0 = (bid - nrb) * 32;        // node base
    const int lane = t & 63;
    const int wv = t >> 6;                    // wave 0..3
    const int l15 = lane & 15, kg = lane >> 4;

    float4v acc[6][2];
#pragma unroll
    for (int g = 0; g < 6; ++g)
#pragma unroll
        for (int j = 0; j < 2; ++j) acc[g][j] = (float4v)0.f;

    int nodeIdx[2];
#pragma unroll
    for (int ni = 0; ni < 2; ++ni) {
        const int nd = row0 + ni * 16 + l15;
        nodeIdx[ni] = (nd < n) ? nd : 0;      // clamp; OOB rows never stored
    }

#pragma unroll
    for (int ks = 0; ks < 4; ++ks) {
        const int koff = ks * 32 + kg * 8;
        half8v b[2];
#pragma unroll
        for (int ni = 0; ni < 2; ++ni) {
            const float* p = x + (size_t)nodeIdx[ni] * FIN_ + koff;
            b[ni] = cvt8(*(const float4*)p, *(const float4*)(p + 4));
        }
#pragma unroll
        for (int g = 0; g < 6; ++g) {
            const int feat = (wv + 4 * g) * 16 + l15;
            const float* p = W + (size_t)feat * FIN_ + koff;
            const half8v a = cvt8(*(const float4*)p, *(const float4*)(p + 4));
            acc[g][0] = __builtin_amdgcn_mfma_f32_16x16x32_f16(a, b[0], acc[g][0], 0, 0, 0);
            acc[g][1] = __builtin_amdgcn_mfma_f32_16x16x32_f16(a, b[1], acc[g][1], 0, 0, 0);
        }
    }

    // ---- 3-phase transpose epilogue (ph = fsel) ----
    for (int ph = 0; ph < 3; ++ph) {
        const float s = (ph == 0) ? 0.25f : 1.0f;   // Fh^-0.5 on q only
#pragma unroll
        for (int g2 = 0; g2 < 2; ++g2) {
            const int g = 2 * ph + g2;
            const int fb = (wv + 4 * g2) * 16 + kg * 4;   // feat within 128-phase
#pragma unroll
            for (int ni = 0; ni < 2; ++ni) {
                const int nl = ni * 16 + l15;             // 0..31
                union { ushort4 u; _Float16 f[4]; } pk;
#pragma unroll
                for (int r = 0; r < 4; ++r) pk.f[r] = (_Float16)(acc[g][ni][r] * s);
                *(ushort4*)&T[nl][fb] = pk.u;
            }
        }
        __syncthreads();
#pragma unroll
        for (int i = 0; i < 2; ++i) {
            const int u = t + i * 256;        // 512 16B-units = 32 x 128
            const int nl = u >> 4;
            const int cs = (u & 15) * 8;
            const int ng = row0 + nl;
            if (ng < n) {
                const half8v val = *(const half8v*)&T[nl][cs];
                if (ph == 0)      *(half8v*)&qb[(size_t)ng * 128 + cs] = val;
                else if (ph == 1) *(half8v*)&kv[(size_t)ng * 256 + cs] = val;
                else              *(half8v*)&kv[(size_t)ng * 256 + 128 + cs] = val;
            }
        }
        __syncthreads();
    }
}

__device__ __forceinline__ float dot16(uint4 k0, uint4 k1, const half2v* q) {
#if __has_builtin(__builtin_amdgcn_fdot2)
    float s = __builtin_amdgcn_fdot2(u2h(k0.x), q[0], 0.f, false);
    s = __builtin_amdgcn_fdot2(u2h(k0.y), q[1], s, false);
    s = __builtin_amdgcn_fdot2(u2h(k0.z), q[2], s, false);
    s = __builtin_amdgcn_fdot2(u2h(k0.w), q[3], s, false);
    s = __builtin_amdgcn_fdot2(u2h(k1.x), q[4], s, false);
    s = __builtin_amdgcn_fdot2(u2h(k1.y), q[5], s, false);
    s = __builtin_amdgcn_fdot2(u2h(k1.z), q[6], s, false);
    s = __builtin_amdgcn_fdot2(u2h(k1.w), q[7], s, false);
    return s;
#else
    half2v a = u2h(k0.x) * q[0];
    a += u2h(k0.y) * q[1];
    a += u2h(k0.z) * q[2];
    a += u2h(k0.w) * q[3];
    a += u2h(k1.x) * q[4];
    a += u2h(k1.y) * q[5];
    a += u2h(k1.z) * q[6];
    a += u2h(k1.w) * q[7];
    return (float)a[0] + (float)a[1];
#endif
}

// ---------------- edge-parallel attention, f16 kv (proven r9 kernel, at its floor) ----
__global__ __launch_bounds__(256) void attn_edges_ep(const _Float16* __restrict__ qb,
                                                     const _Float16* __restrict__ kv,
                                                     const int* __restrict__ rowptr,
                                                     const int* __restrict__ dest,
                                                     float* __restrict__ out, int n) {
    const int wave = threadIdx.x >> 6;
    const int node = blockIdx.x * 4 + wave;
    if (node >= n) return;
    const int lane = threadIdx.x & 63;
    const int j = lane >> 3;
    const int h = lane & 7;
    const int ppos = ((j & 1) << 3) | ((j & 2) << 1) | ((j & 4) >> 1);
    float* outp = &out[(size_t)node * FIN_ + h * 16 + ppos];

    const int e0 = rowptr[node];
    const int e1 = rowptr[node + 1];
    if (e0 == e1) {
        *(float2*)outp = make_float2(0.f, 0.f);
        return;
    }

    half2v qh[8];
    {
        const uint4 q0 = *(const uint4*)(qb + (size_t)node * 128 + h * 16);
        const uint4 q1 = *(const uint4*)(qb + (size_t)node * 128 + h * 16 + 8);
        qh[0] = u2h(q0.x); qh[1] = u2h(q0.y); qh[2] = u2h(q0.z); qh[3] = u2h(q0.w);
        qh[4] = u2h(q1.x); qh[5] = u2h(q1.y); qh[6] = u2h(q1.z); qh[7] = u2h(q1.w);
    }

    float lsum = 0.f;
    half2v a8[8];
#pragma unroll
    for (int i = 0; i < 8; ++i) a8[i] = (half2v)(_Float16)0;

    const int hoff = h << 4;
    for (int eb = e0; eb < e1; eb += 16) {
        const int eA = eb + j;
        const int eB = eb + 8 + j;
        const bool vA = eA < e1;
        const bool vB = eB < e1;
        const unsigned dA = (unsigned)dest[vA ? eA : (e1 - 1)];
        const unsigned dB = (unsigned)dest[vB ? eB : (e1 - 1)];
        const unsigned offA = (dA << 8) + hoff;
        const unsigned offB = (dB << 8) + hoff;
        const uint4 k0A = *(const uint4*)(kv + offA);
        const uint4 k1A = *(const uint4*)(kv + offA + 8);
        const uint4 v0A = *(const uint4*)(kv + offA + 128);
        const uint4 v1A = *(const uint4*)(kv + offA + 136);
        const uint4 k0B = *(const uint4*)(kv + offB);
        const uint4 k1B = *(const uint4*)(kv + offB + 8);
        const uint4 v0B = *(const uint4*)(kv + offB + 128);
        const uint4 v1B = *(const uint4*)(kv + offB + 136);

        const float sA = dot16(k0A, k1A, qh);
        const float sB = dot16(k0B, k1B, qh);
        const float pA = vA ? __expf(sA) : 0.f;
        const float pB = vB ? __expf(sB) : 0.f;
        lsum += pA + pB;

        const _Float16 ha = (_Float16)pA, hb = (_Float16)pB;
        const half2v pa = {ha, ha}, pb = {hb, hb};
        a8[0] += pa * u2h(v0A.x) + pb * u2h(v0B.x);
        a8[1] += pa * u2h(v0A.y) + pb * u2h(v0B.y);
        a8[2] += pa * u2h(v0A.z) + pb * u2h(v0B.z);
        a8[3] += pa * u2h(v0A.w) + pb * u2h(v0B.w);
        a8[4] += pa * u2h(v1A.x) + pb * u2h(v1B.x);
        a8[5] += pa * u2h(v1A.y) + pb * u2h(v1B.y);
        a8[6] += pa * u2h(v1A.z) + pb * u2h(v1B.z);
        a8[7] += pa * u2h(v1A.w) + pb * u2h(v1B.w);
    }

    lsum += __shfl_xor(lsum, 8);
    lsum += __shfl_xor(lsum, 16);
    lsum += __shfl_xor(lsum, 32);

    float a16[16];
#pragma unroll
    for (int i = 0; i < 8; ++i) {
        a16[2 * i]     = (float)a8[i][0];
        a16[2 * i + 1] = (float)a8[i][1];
    }

    float r8[8];
    {
        const bool b = (j & 1) != 0;
#pragma unroll
        for (int i = 0; i < 8; ++i) {
            const float keep = b ? a16[i + 8] : a16[i];
            const float send = b ? a16[i] : a16[i + 8];
            r8[i] = keep + __shfl_xor(send, 8);
        }
    }
    float r4[4];
    {
        const bool b = (j & 2) != 0;
#pragma unroll
        for (int i = 0; i < 4; ++i) {
            const float keep = b ? r8[i + 4] : r8[i];
            const float send = b ? r8[i] : r8[i + 4];
            r4[i] = keep + __shfl_xor(send, 16);
        }
    }
    float r2[2];
    {
        const bool b = (j & 4) != 0;
#pragma unroll
        for (int i = 0; i < 2; ++i) {
            const float keep = b ? r4[i + 2] : r4[i];
            const float send = b ? r4[i] : r4[i + 2];
            r2[i] = keep + __shfl_xor(send, 32);
        }
    }

    const float inv = (lsum > 0.f) ? 1.f / lsum : 0.f;
    *(float2*)outp = make_float2(r2[0] * inv, r2[1] * inv);
}

extern "C" void kernel_launch(void* const* d_in, const int* in_sizes, int n_in,
                              void* d_out, int out_size, void* d_ws, size_t ws_size,
                              hipStream_t stream) {
    const float* x = (const float*)d_in[0];
    const float* W = (const float*)d_in[1];
    // d_in[2] = batch : unused by the reference
    const int* ei = (const int*)d_in[3];

    const int n = in_sizes[0] / FIN_;     // 50000
    const int nE = in_sizes[3] / 2;       // 800000
    const int* src = ei;
    const int* dest = ei + nE;

    char* w = (char*)d_ws;
    _Float16* qb = (_Float16*)w;   w += (size_t)n * 128 * 2;   // 12.8 MB
    _Float16* kv = (_Float16*)w;   w += (size_t)n * 256 * 2;   // 25.6 MB
    int* rowptr = (int*)w;
    float* out = (float*)d_out;

    const int nrb = (n + 1 + 255) / 256;          // 196 rowptr blocks (first)
    const int ngb = (n + 31) / 32;                // 1563 gemm tiles
    prep_kernel<<<nrb + ngb, 256, 0, stream>>>(x, W, qb, kv, src, rowptr, n, nE, nrb);

    attn_edges_ep<<<(n + 3) / 4, 256, 0, stream>>>(qb, kv, rowptr, dest, out, n);
}